// Round 1
// baseline (52.993 us; speedup 1.0000x reference)
//
#include <hip/hip_runtime.h>

#define NCELLS (4*4*128*128)   // 262144 cells
#define NSAMP  100
#define BLOCK  256
#define NBLK   (NCELLS / BLOCK) // 1024

// murmur3 finalizer — bijective, strong avalanche; counter-based RNG
__device__ __forceinline__ unsigned fmix32(unsigned h) {
    h ^= h >> 16;
    h *= 0x85ebca6bu;
    h ^= h >> 13;
    h *= 0xc2b2ae35u;
    h ^= h >> 16;
    return h;
}

// u32 -> open-interval (0,1) float with 24-bit mantissa
__device__ __forceinline__ float u01(unsigned h) {
    return ((float)(h >> 8) + 0.5f) * (1.0f / 16777216.0f);
}

__global__ __launch_bounds__(BLOCK) void crps_mc_kernel(
    const float* __restrict__ alpha,
    const float* __restrict__ beta,
    const float* __restrict__ weights,
    const float* __restrict__ y_true,
    float* __restrict__ partial)
{
    const int cell = blockIdx.x * BLOCK + threadIdx.x;

    // M=4 innermost -> one float4 per cell, fully coalesced (16B/lane)
    const float4 a4 = reinterpret_cast<const float4*>(alpha)[cell];
    const float4 b4 = reinterpret_cast<const float4*>(beta)[cell];
    const float y   = y_true[cell];

    // mixture CDF (weights are pre-normalized on host)
    const float w0 = weights[0], w1 = weights[1], w2 = weights[2];
    const float c0 = w0, c1 = w0 + w1, c2 = w0 + w1 + w2;

    const float ia0 = 1.0f / a4.x, ia1 = 1.0f / a4.y, ia2 = 1.0f / a4.z, ia3 = 1.0f / a4.w;
    const float ib0 = 1.0f / b4.x, ib1 = 1.0f / b4.y, ib2 = 1.0f / b4.z, ib3 = 1.0f / b4.w;

    float t1 = 0.0f;     // sum |x - y|
    float t2 = 0.0f;     // sum |x_s - x_{s-1}|  (99 consecutive pairs, unbiased for E|X-X'|)
    float xprev = 0.0f;

    const unsigned base = (unsigned)cell * 200u;  // unique counter space per cell

    #pragma unroll 4
    for (int s = 0; s < NSAMP; ++s) {
        const unsigned hc = fmix32(base + 2u * (unsigned)s + 0x9e3779b9u);
        const unsigned hu = fmix32(base + 2u * (unsigned)s + 1u + 0x7f4a7c15u);
        const float uc = u01(hc);   // component selector
        const float uu = u01(hu);   // inverse-CDF uniform

        // categorical via CDF compares -> cndmask selects (no divergence, no scratch)
        float ia = ia0, ib = ib0;
        if (uc >= c0) { ia = ia1; ib = ib1; }
        if (uc >= c1) { ia = ia2; ib = ib2; }
        if (uc >= c2) { ia = ia3; ib = ib3; }

        // x = (1 - (1-u)^(1/b))^(1/a)   via v_log_f32 / v_exp_f32 (log2/exp2)
        const float v = 1.0f - uu;                                        // (0,1)
        const float p = __builtin_amdgcn_exp2f(ib * __builtin_amdgcn_logf(v));
        const float w = fmaxf(1.0f - p, 0.0f);                            // guard approx-error w<0 -> NaN
        const float x = __builtin_amdgcn_exp2f(ia * __builtin_amdgcn_logf(w)); // w==0 -> exp2(-inf)=0, ok

        t1 += fabsf(x - y);
        if (s > 0) t2 += fabsf(x - xprev);
        xprev = x;
    }

    float val = t1 * (1.0f / NSAMP) - 0.5f * t2 * (1.0f / (NSAMP - 1));

    // wave64 shuffle reduce
    #pragma unroll
    for (int off = 32; off > 0; off >>= 1)
        val += __shfl_down(val, off, 64);

    __shared__ float red[BLOCK / 64];
    if ((threadIdx.x & 63) == 0) red[threadIdx.x >> 6] = val;
    __syncthreads();
    if (threadIdx.x == 0) {
        float s = 0.0f;
        #pragma unroll
        for (int i = 0; i < BLOCK / 64; ++i) s += red[i];
        partial[blockIdx.x] = s;
    }
}

__global__ __launch_bounds__(BLOCK) void crps_reduce_kernel(
    const float* __restrict__ partial, float* __restrict__ out)
{
    const int t = threadIdx.x;
    float v = partial[t] + partial[t + 256] + partial[t + 512] + partial[t + 768];
    #pragma unroll
    for (int off = 32; off > 0; off >>= 1)
        v += __shfl_down(v, off, 64);
    __shared__ float red[4];
    if ((t & 63) == 0) red[t >> 6] = v;
    __syncthreads();
    if (t == 0) out[0] = (red[0] + red[1] + red[2] + red[3]) * (1.0f / NCELLS);
}

extern "C" void kernel_launch(void* const* d_in, const int* in_sizes, int n_in,
                              void* d_out, int out_size, void* d_ws, size_t ws_size,
                              hipStream_t stream) {
    // setup_inputs order: alpha, beta, weights, y_true, i_idx, j_idx
    const float* alpha   = (const float*)d_in[0];
    const float* beta    = (const float*)d_in[1];
    const float* weights = (const float*)d_in[2];
    const float* y_true  = (const float*)d_in[3];
    // i_idx / j_idx unused: we use 99 consecutive-sample pairs (same expectation)

    float* partial = (float*)d_ws;  // 1024 floats = 4 KB scratch

    crps_mc_kernel<<<NBLK, BLOCK, 0, stream>>>(alpha, beta, weights, y_true, partial);
    crps_reduce_kernel<<<1, BLOCK, 0, stream>>>(partial, (float*)d_out);
}